// Round 3
// baseline (444.401 us; speedup 1.0000x reference)
//
#include <hip/hip_runtime.h>
#include <math.h>

// CapsLayer dynamic routing, MI355X fp32.
// x: [64, 2048, 8]  W: [2048, 32, 8, 16]  out: [64, 32, 16]
// Never materialize u_hat (256 MB); recompute per routing pass.
// R3: wave-autonomous. lane = n + 32*eh (n = capsule, eh = e-half of 8) so
// softmax over the 32 capsules is a pure in-wave shfl reduction -> ZERO LDS,
// ZERO barriers. x read via wave-uniform scalar loads; W fragment has zero
// intra-wave duplication (full 16KB W[i] per wave); 4 waves/block share W[i]
// via L1, 8 sibling blocks share it via same-XCD L2 (blockIdx = bpg*128+ic).

#define B_TOT 64
#define I_TOT 2048
#define NC    32
#define EV    16
#define OD    (NC*EV)      // 512
#define ICH   16           // i's per wave
#define NIC   (I_TOT/ICH)  // 128

__device__ __forceinline__ void fma4(float4& acc, float a, const float4& w) {
    acc.x = fmaf(a, w.x, acc.x);
    acc.y = fmaf(a, w.y, acc.y);
    acc.z = fmaf(a, w.z, acc.z);
    acc.w = fmaf(a, w.w, acc.w);
}
__device__ __forceinline__ float dot4(const float4& a, const float4& b) {
    return a.x*b.x + a.y*b.y + a.z*b.z + a.w*b.w;
}

// MODE 0: c uniform (iter 0)                    -> P partials
// MODE 1: a = u.v0, softmax(a), store a to aws  -> P partials
// MODE 2: a = u.v1 + a0(from aws), softmax      -> P partials
template <int MODE>
__global__ __launch_bounds__(256, 4)
void route_pass(const float* __restrict__ x, const float* __restrict__ W,
                float* __restrict__ P, const float* __restrict__ vin,
                float* __restrict__ aws)
{
    const int t    = threadIdx.x;
    const int w    = __builtin_amdgcn_readfirstlane(t >> 6);  // wave 0..3 (uniform)
    const int lane = t & 63;
    const int n    = lane & 31;   // capsule
    const int eh   = lane >> 5;   // e-half (8 e's per lane)

    const int ic  = blockIdx.x & (NIC - 1);  // 0..127 ; XCD = f(ic) only
    const int bpg = blockIdx.x >> 7;         // 0..7
    const int i0  = ic * ICH;
    const int b0  = bpg * 8 + w * 2;         // wave-uniform batch rows
    const int b1  = b0 + 1;

    // wave-uniform x row pointers -> scalar loads
    const float* xr0 = x + ((size_t)b0 * I_TOT + i0) * 8;
    const float* xr1 = x + ((size_t)b1 * I_TOT + i0) * 8;

    float4 vr00, vr01, vr10, vr11;
    if (MODE >= 1) {
        vr00 = *(const float4*)&vin[b0 * OD + n * EV + eh * 8];
        vr01 = *(const float4*)&vin[b0 * OD + n * EV + eh * 8 + 4];
        vr10 = *(const float4*)&vin[b1 * OD + n * EV + eh * 8];
        vr11 = *(const float4*)&vin[b1 * OD + n * EV + eh * 8 + 4];
    }

    float4 s0a = {0,0,0,0}, s0b = {0,0,0,0};
    float4 s1a = {0,0,0,0}, s1b = {0,0,0,0};

    const float* Wp = W + (size_t)i0 * 4096 + n * 128 + eh * 8;

    for (int ii = 0; ii < ICH; ++ii) {
        const int i = i0 + ii;
        // ---- W[i] fragment: 8 e's x 8 d's, zero intra-wave duplication ----
        float4 wa[8], wb[8];
        #pragma unroll
        for (int d = 0; d < 8; ++d) {
            wa[d] = *(const float4*)&Wp[ii * 4096 + d * 16];
            wb[d] = *(const float4*)&Wp[ii * 4096 + d * 16 + 4];
        }
        // ---- u for 2 batch rows (x via scalar loads) ----
        float4 u0a = {0,0,0,0}, u0b = {0,0,0,0};
        float4 u1a = {0,0,0,0}, u1b = {0,0,0,0};
        #pragma unroll
        for (int d = 0; d < 8; ++d) {
            float x0 = xr0[ii * 8 + d];
            float x1 = xr1[ii * 8 + d];
            fma4(u0a, x0, wa[d]); fma4(u0b, x0, wb[d]);
            fma4(u1a, x1, wa[d]); fma4(u1b, x1, wb[d]);
        }

        if (MODE == 0) {
            s0a.x += u0a.x; s0a.y += u0a.y; s0a.z += u0a.z; s0a.w += u0a.w;
            s0b.x += u0b.x; s0b.y += u0b.y; s0b.z += u0b.z; s0b.w += u0b.w;
            s1a.x += u1a.x; s1a.y += u1a.y; s1a.z += u1a.z; s1a.w += u1a.w;
            s1b.x += u1b.x; s1b.y += u1b.y; s1b.z += u1b.z; s1b.w += u1b.w;
        } else {
            // ---- logits: dot(u, v) over 16 e = 8 in-thread + shfl over eh ----
            float a0 = dot4(u0a, vr00) + dot4(u0b, vr01);
            float a1 = dot4(u1a, vr10) + dot4(u1b, vr11);
            a0 += __shfl_xor(a0, 32, 64);
            a1 += __shfl_xor(a1, 32, 64);
            if (MODE == 2) {
                a0 += aws[((size_t)i * B_TOT + b0) * NC + n];
                a1 += aws[((size_t)i * B_TOT + b1) * NC + n];
            }
            if (MODE == 1 && eh == 0) {
                aws[((size_t)i * B_TOT + b0) * NC + n] = a0;
                aws[((size_t)i * B_TOT + b1) * NC + n] = a1;
            }
            // ---- softmax over n: fully in-wave (n = lane bits 0..4) ----
            float e0 = __expf(a0), e1 = __expf(a1);
            float p0 = e0, p1 = e1;
            p0 += __shfl_xor(p0, 1, 64);  p1 += __shfl_xor(p1, 1, 64);
            p0 += __shfl_xor(p0, 2, 64);  p1 += __shfl_xor(p1, 2, 64);
            p0 += __shfl_xor(p0, 4, 64);  p1 += __shfl_xor(p1, 4, 64);
            p0 += __shfl_xor(p0, 8, 64);  p1 += __shfl_xor(p1, 8, 64);
            p0 += __shfl_xor(p0, 16, 64); p1 += __shfl_xor(p1, 16, 64);
            float c0 = e0 / p0, c1 = e1 / p1;
            fma4(s0a, c0, u0a); fma4(s0b, c0, u0b);
            fma4(s1a, c1, u1a); fma4(s1b, c1, u1b);
        }
    }

    // ---- partials: P[ic][b][o], o = n*16 + eh*8 + j ----
    float4* p0 = (float4*)&P[((size_t)ic * B_TOT + b0) * OD + n * EV + eh * 8];
    float4* p1 = (float4*)&P[((size_t)ic * B_TOT + b1) * OD + n * EV + eh * 8];
    p0[0] = s0a; p0[1] = s0b;
    p1[0] = s1a; p1[1] = s1b;
}

// Reduce partials over i-chunks, then squash per (b, n). One block per b.
__global__ __launch_bounds__(256, 4)
void reduce_squash(const float* __restrict__ P, float* __restrict__ dst, float pre)
{
    const int b = blockIdx.x;
    const int t = threadIdx.x;
    float s1 = 0.f, s2 = 0.f;
    for (int ic = 0; ic < NIC; ++ic) {
        const float* p = &P[((size_t)ic * B_TOT + b) * OD];
        s1 += p[t];
        s2 += p[t + 256];
    }
    s1 *= pre; s2 *= pre;
    // squared norm over e (16 consecutive lanes)
    float q1 = s1 * s1, q2 = s2 * s2;
    q1 += __shfl_xor(q1, 1, 64);  q2 += __shfl_xor(q2, 1, 64);
    q1 += __shfl_xor(q1, 2, 64);  q2 += __shfl_xor(q2, 2, 64);
    q1 += __shfl_xor(q1, 4, 64);  q2 += __shfl_xor(q2, 4, 64);
    q1 += __shfl_xor(q1, 8, 64);  q2 += __shfl_xor(q2, 8, 64);
    float sc1 = q1 / ((1.0f + q1) * sqrtf(q1));
    float sc2 = q2 / ((1.0f + q2) * sqrtf(q2));
    dst[b * OD + t]       = s1 * sc1;
    dst[b * OD + t + 256] = s2 * sc2;
}

extern "C" void kernel_launch(void* const* d_in, const int* in_sizes, int n_in,
                              void* d_out, int out_size, void* d_ws, size_t ws_size,
                              hipStream_t stream) {
    const float* x = (const float*)d_in[0];
    const float* W = (const float*)d_in[1];
    float* out = (float*)d_out;

    char* ws = (char*)d_ws;
    float* P   = (float*)ws;                               // 128*64*512*4 = 16 MB
    float* aws = (float*)(ws + (size_t)16 * 1024 * 1024);  // 2048*64*32*4 = 16 MB
    float* v0  = (float*)(ws + (size_t)32 * 1024 * 1024);  // 64*512*4     = 128 KB
    float* v1  = v0 + B_TOT * OD;

    dim3 grid(8 * NIC), blk(256);   // 1024 blocks, 4 autonomous waves each

    // iter 0: uniform c = 1/32 (applied as pre-scale in reduce)
    route_pass<0><<<grid, blk, 0, stream>>>(x, W, P, nullptr, nullptr);
    reduce_squash<<<B_TOT, 256, 0, stream>>>(P, v0, 1.0f / 32.0f);
    // iter 1: c = softmax(dot(u, v0)); store logits a0
    route_pass<1><<<grid, blk, 0, stream>>>(x, W, P, v0, aws);
    reduce_squash<<<B_TOT, 256, 0, stream>>>(P, v1, 1.0f);
    // iter 2: c = softmax(a0 + dot(u, v1)); final
    route_pass<2><<<grid, blk, 0, stream>>>(x, W, P, v1, aws);
    reduce_squash<<<B_TOT, 256, 0, stream>>>(P, out, 1.0f);
}